// Round 3
// baseline (356.471 us; speedup 1.0000x reference)
//
#include <hip/hip_runtime.h>
#include <math.h>

#define TINY_EPS 1.1920928955078125e-07f  // np.finfo(np.float32).eps = 2^-23

// Pure-scalar build: no ext_vector types anywhere. Every op below is the
// same IEEE fp32 op the reference performs (fp contract(off) throughout);
// arrays are only indexed with compile-time constants under #pragma unroll,
// so everything lives in registers as straight-line scalar SSA.

// custom_round: floor((x - copysign(TINY,x)) + 0.5).
// (v - cs) is a single IEEE sub == ref's x - sign(x)*TINY.
static __device__ __forceinline__ float cround1(float v) {
#pragma clang fp contract(off)
    float cs = copysignf(TINY_EPS, v);
    float t = (v - cs) + 0.5f;
    return floorf(t);
}

// One D8 branch candidate on 8 scalars: y = f + parity-masked g_x flip.
// SHIFTED folds the +0.5 coset bias into the per-component add (bit-exact:
// f and step are integers, so f+(step+0.5) == (f+step)+0.5 exactly; and
// f + 0.0 == f bitwise since f is never -0).
template <bool SHIFTED>
static __device__ __forceinline__ void d8_cand8(const float x[8], float y[8]) {
#pragma clang fp contract(off)
    float f[8], w[8];
#pragma unroll
    for (int i = 0; i < 8; ++i) {
        f[i] = cround1(x[i]);
        w[i] = x[i] - f[i];               // exact (Sterbenz-type)
    }

    // parity of the integer sum — exact small ints, any association
    float s = ((f[0] + f[1]) + (f[2] + f[3])) + ((f[4] + f[5]) + (f[6] + f[7]));
    int odd = ((int)s) & 1;

    // argmax |w|, FIRST index on ties — tournament, left wins ties (>=),
    // == jnp.argmax first-occurrence semantics.
    float v01, v23, v45, v67; int k01, k23, k45, k67;
    { bool ge = fabsf(w[0]) >= fabsf(w[1]); v01 = ge ? w[0] : w[1]; k01 = ge ? 0 : 1; }
    { bool ge = fabsf(w[2]) >= fabsf(w[3]); v23 = ge ? w[2] : w[3]; k23 = ge ? 2 : 3; }
    { bool ge = fabsf(w[4]) >= fabsf(w[5]); v45 = ge ? w[4] : w[5]; k45 = ge ? 4 : 5; }
    { bool ge = fabsf(w[6]) >= fabsf(w[7]); v67 = ge ? w[6] : w[7]; k67 = ge ? 6 : 7; }
    float va, vb; int ka, kb;
    { bool ge = fabsf(v01) >= fabsf(v23); va = ge ? v01 : v23; ka = ge ? k01 : k23; }
    { bool ge = fabsf(v45) >= fabsf(v67); vb = ge ? v45 : v67; kb = ge ? k45 : k67; }
    int k; float wk;
    { bool ge = fabsf(va) >= fabsf(vb); wk = ge ? va : vb; k = ge ? ka : kb; }

    // step = sign(wk) for wk!=0; for wk==0 all |w|==0 so k==0 and the tie
    // x-value is x[0] (never -0.0 on any reachable path): ref step there is
    // -1 for x[0]>=0, +1 for x[0]<0 == sign(-x[0]).
    float tsel = (wk != 0.0f) ? wk : -x[0];
    float sf = __int_as_float(0x3f800000 | (__float_as_int(tsel) & 0x80000000u));
    float sfm = odd ? sf : 0.0f;          // flip only when parity is odd

    const float bias = SHIFTED ? 0.5f : 0.0f;
    const float fb   = SHIFTED ? (sfm + 0.5f) : sfm;   // exact
#pragma unroll
    for (int i = 0; i < 8; ++i) {
        y[i] = f[i] + ((k == i) ? fb : bias);          // exact int(+bias) adds
    }
}

static __device__ __forceinline__ void closest_point_E8s(const float x[8], float y[8]) {
#pragma clang fp contract(off)
    float y0[8], y1[8], xs[8];
    d8_cand8<false>(x, y0);
#pragma unroll
    for (int i = 0; i < 8; ++i) xs[i] = x[i] - 0.5f;   // exact in our range
    d8_cand8<true>(xs, y1);            // (cand)+0.5 already folded in

    // Distances from the ORIGINAL x; sums in numpy's exact pairwise order.
    float q0[8], q1[8];
#pragma unroll
    for (int i = 0; i < 8; ++i) {
        float e0 = x[i] - y0[i];
        q0[i] = e0 * e0;
        float e1 = x[i] - y1[i];
        q1[i] = e1 * e1;
    }
    float D0 = ((q0[0] + q0[1]) + (q0[2] + q0[3])) + ((q0[4] + q0[5]) + (q0[6] + q0[7]));
    float D1 = ((q1[0] + q1[1]) + (q1[2] + q1[3])) + ((q1[4] + q1[5]) + (q1[6] + q1[7]));
    bool pick0 = (D0 < D1);               // tie -> y1, as in ref
#pragma unroll
    for (int i = 0; i < 8; ++i) {
        y[i] = pick0 ? y0[i] : y1[i];
    }
}

__global__ __launch_bounds__(256)
void lattice_quant_kernel(const float* __restrict__ x,
                          const float* __restrict__ beta_p,
                          const float* __restrict__ eps,
                          float* __restrict__ out, int n) {
#pragma clang fp contract(off)
    int row = blockIdx.x * blockDim.x + threadIdx.x;
    if (row >= n) return;
    float beta = beta_p[0];

    const float4* px = (const float4*)(x + (size_t)row * 8);
    float4 a0 = px[0], a1 = px[1];
    const float4* pe = (const float4*)eps;
    float4 e0 = pe[0], e1 = pe[1];
    float ev[8] = { e0.x, e0.y, e0.z, e0.w, e1.x, e1.y, e1.z, e1.w };

    float xl[8] = { a0.x, a0.y, a0.z, a0.w, a1.x, a1.y, a1.z, a1.w };
    if (beta != 1.0f) {                   // wave-uniform; beta==1 skips divs
#pragma unroll
        for (int i = 0; i < 8; ++i) xl[i] = xl[i] / beta;
    }

    float xhat[8];

    float wgt = 1.0f;
#pragma unroll
    for (int l = 0; l < 3; ++l) {
        // ---- encode: quantize to E8 ----
        float xin[8], lat[8];
#pragma unroll
        for (int i = 0; i < 8; ++i) xin[i] = xl[i] + ev[i];
        closest_point_E8s(xin, lat);

        // u = lat @ G_inv via forward substitution (exact fp32 == ref matmul)
        float u0 = 0.5f * lat[0];
        float u1 = lat[1] + u0;
        float u2 = lat[2] + u1;
        float u3 = lat[3] + u2;
        float u4 = lat[4] + u3;
        float u5 = lat[5] + u4;
        float u6 = lat[6] + u5;
        float s6 = ((u0 + u1) + (u2 + u3)) + ((u4 + u5) + u6);
        float u7 = fmaf(2.0f, lat[7], -s6);   // 2*lat7 exact -> == mul+sub
        float uv[8] = { u0, u1, u2, u3, u4, u5, u6, u7 };

        // b = custom_round(fmod(u, 4)); fmod exact on quarter grid; the fma
        // is exact-by-proof (trunc*4 exact), so fused == ref's separate ops.
        // NOTE: u contains half/quarter-integers (u0 = lat0/2), so the cround
        // here is NOT removable (cround(3.5)==4 quirk included).
        float b[8];
#pragma unroll
        for (int i = 0; i < 8; ++i) {
            float q = uv[i] * 0.25f;                 // exact (pow2)
            float t4 = truncf(q);
            float m = fmaf(t4, -4.0f, uv[i]);        // == fmod(u,4) exact
            b[i] = cround1(m);
        }

        // ---- decode this layer: Gb = b @ rows (sparse, exact ints) ----
        float h = 0.5f * b[7];
        float Gb[8];
        Gb[0] = 2.0f * b[0] - b[1] + h;
        Gb[1] = b[1] - b[2] + h;
        Gb[2] = b[2] - b[3] + h;
        Gb[3] = b[3] - b[4] + h;
        Gb[4] = b[4] - b[5] + h;
        Gb[5] = b[5] - b[6] + h;
        Gb[6] = b[6] + h;
        Gb[7] = h;

        float gq[8], cp[8];
#pragma unroll
        for (int i = 0; i < 8; ++i) gq[i] = Gb[i] * 0.25f;
        closest_point_E8s(gq, cp);

#pragma unroll
        for (int i = 0; i < 8; ++i) {
            float xi = fmaf(cp[i], -4.0f, Gb[i]);    // Gb - 4*cp (exact)
            if (l == 0) {
                // layer 0: ref computes 0 + 1*xi = xi bitwise (xi never -0),
                // so a plain copy is bit-exact.
                xhat[i] = xi;
            } else {
                xhat[i] = fmaf(xi, wgt, xhat[i]);    // += wgt*xi (exact)
            }
        }

        // next layer input: lat / Q (exact)
#pragma unroll
        for (int i = 0; i < 8; ++i) xl[i] = lat[i] * 0.25f;
        wgt *= 4.0f;
    }

    // epilogue: beta==1 -> x*1 == x bitwise, skip the mul (wave-uniform)
    float o[8];
    if (beta != 1.0f) {
#pragma unroll
        for (int i = 0; i < 8; ++i) o[i] = xhat[i] * beta;
    } else {
#pragma unroll
        for (int i = 0; i < 8; ++i) o[i] = xhat[i];
    }
    float4 o0, o1;
    o0.x = o[0]; o0.y = o[1]; o0.z = o[2]; o0.w = o[3];
    o1.x = o[4]; o1.y = o[5]; o1.z = o[6]; o1.w = o[7];
    float4* po = (float4*)(out + (size_t)row * 8);
    po[0] = o0; po[1] = o1;
}

extern "C" void kernel_launch(void* const* d_in, const int* in_sizes, int n_in,
                              void* d_out, int out_size, void* d_ws, size_t ws_size,
                              hipStream_t stream) {
    const float* x      = (const float*)d_in[0];
    const float* beta_p = (const float*)d_in[1];
    // d_in[2] = G, d_in[3] = G_inv — structure hardcoded (fixed by reference)
    const float* eps    = (const float*)d_in[4];
    float* out = (float*)d_out;
    int n = in_sizes[0] / 8;
    int block = 256;
    int grid = (n + block - 1) / block;
    lattice_quant_kernel<<<grid, block, 0, stream>>>(x, beta_p, eps, out, n);
}

// Round 4
// 332.499 us; speedup vs baseline: 1.0721x; 1.0721x over previous
//
#include <hip/hip_runtime.h>
#include <math.h>

#define TINY_EPS 1.1920928955078125e-07f  // np.finfo(np.float32).eps = 2^-23

typedef float float2v __attribute__((ext_vector_type(2)));

// Native vector ops: on gfx950 (hasPackedFP32Ops) LLVM can select v_pk_*_f32
// from <2 x float> IR with inline-const operands and neg/abs modifiers folded.
// All FP stays IEEE-exact: fp contract(off) everywhere; explicit single-rounded
// FMA only via __builtin_elementwise_fma where exactness is proven.
// Round-3 A/B proved this vector form beats pure-scalar by 14% (185 vs 212 us).
static __device__ __forceinline__ float2v vfma(float2v a, float2v b, float2v c) {
    return __builtin_elementwise_fma(a, b, c);
}
static __device__ __forceinline__ float2v splat(float s) { return (float2v){s, s}; }

// custom_round per component: floor((x - copysign(TINY,x)) + 0.5).
// (v - cs) is a single IEEE sub == ref's x - sign(x)*TINY.
static __device__ __forceinline__ float2v croundv(float2v v) {
#pragma clang fp contract(off)
    float2v cs = { copysignf(TINY_EPS, v.x), copysignf(TINY_EPS, v.y) };
    float2v t = (v - cs) + splat(0.5f);
    return (float2v){ floorf(t.x), floorf(t.y) };
}

// One D8 branch candidate: y = f + parity-masked g_x flip (+0.5 coset bias
// folded into the select constants when SHIFTED — bit-exact: f and c are
// integers, so f+(c+0.5) == (f+c)+0.5 exactly).
template <bool SHIFTED>
static __device__ __forceinline__ void d8_candidate(const float2v in[4], float2v y[4]) {
#pragma clang fp contract(off)
    float2v f[4], w[4];
#pragma unroll
    for (int p = 0; p < 4; ++p) {
        f[p] = croundv(in[p]);
        w[p] = in[p] - f[p];              // exact (Sterbenz-type)
    }

    // parity of the integer sum — exact small ints, order-free
    float2v sp = (f[0] + f[1]) + (f[2] + f[3]);
    float s = sp.x + sp.y;
    int odd = ((int)s) & 1;

    // argmax |w|, FIRST index on ties — tournament tree (dep depth 3).
    // Left wins ties (>=) => lowest-indexed maximum, == jnp.argmax semantics.
    float v01, v23, v45, v67; int k01, k23, k45, k67;
    { bool ge = fabsf(w[0].x) >= fabsf(w[0].y); v01 = ge ? w[0].x : w[0].y; k01 = ge ? 0 : 1; }
    { bool ge = fabsf(w[1].x) >= fabsf(w[1].y); v23 = ge ? w[1].x : w[1].y; k23 = ge ? 2 : 3; }
    { bool ge = fabsf(w[2].x) >= fabsf(w[2].y); v45 = ge ? w[2].x : w[2].y; k45 = ge ? 4 : 5; }
    { bool ge = fabsf(w[3].x) >= fabsf(w[3].y); v67 = ge ? w[3].x : w[3].y; k67 = ge ? 6 : 7; }
    float va, vb; int ka, kb;
    { bool ge = fabsf(v01) >= fabsf(v23); va = ge ? v01 : v23; ka = ge ? k01 : k23; }
    { bool ge = fabsf(v45) >= fabsf(v67); vb = ge ? v45 : v67; kb = ge ? k45 : k67; }
    int k; float wk;
    { bool ge = fabsf(va) >= fabsf(vb); wk = ge ? va : vb; k = ge ? ka : kb; }

    // step = sign(wk) for wk!=0; for wk==0 all |w|==0 so k==0 and the tie
    // x-value is in[0].x (never -0.0 on any reachable path).
    float tsel = (wk != 0.0f) ? wk : -in[0].x;
    float sf = __int_as_float(0x3f800000 | (__float_as_int(tsel) & 0x80000000u));
    float sfm = odd ? sf : 0.0f;          // flip only when parity is odd

    const float bias = SHIFTED ? 0.5f : 0.0f;
    const float fb   = SHIFTED ? (sfm + 0.5f) : sfm;   // exact
#pragma unroll
    for (int p = 0; p < 4; ++p) {
        float2v c;
        c.x = (k == 2 * p)     ? fb : bias;
        c.y = (k == 2 * p + 1) ? fb : bias;
        y[p] = f[p] + c;                   // integers (+bias): exact
    }
}

static __device__ __forceinline__ void closest_point_E8v(const float2v x[4], float2v y[4]) {
#pragma clang fp contract(off)
    float2v y0[4], y1[4], xs[4];
    d8_candidate<false>(x, y0);
#pragma unroll
    for (int p = 0; p < 4; ++p) xs[p] = x[p] - splat(0.5f);
    d8_candidate<true>(xs, y1);            // (cand)+0.5 already folded in

    // Distances from the ORIGINAL x; packed subs/squares, scalar tree adds in
    // numpy's exact pairwise order — vector-element pairs ARE the base pairs.
    float2v q0[4], q1[4];
#pragma unroll
    for (int p = 0; p < 4; ++p) {
        float2v e0 = x[p] - y0[p];
        q0[p] = e0 * e0;
        float2v e1 = x[p] - y1[p];
        q1[p] = e1 * e1;
    }
    float D0 = ((q0[0].x + q0[0].y) + (q0[1].x + q0[1].y)) +
               ((q0[2].x + q0[2].y) + (q0[3].x + q0[3].y));
    float D1 = ((q1[0].x + q1[0].y) + (q1[1].x + q1[1].y)) +
               ((q1[2].x + q1[2].y) + (q1[3].x + q1[3].y));
    bool pick0 = (D0 < D1);               // tie -> y1, as in ref
#pragma unroll
    for (int p = 0; p < 4; ++p) {
        float2v r;
        r.x = pick0 ? y0[p].x : y1[p].x;
        r.y = pick0 ? y0[p].y : y1[p].y;
        y[p] = r;
    }
}

// (256, 2): tell the backend 2 waves/EU is acceptable (VGPR cap 256) so the
// scheduler stops trading instruction count for occupancy. Rounds 1 vs 2
// proved issue saturation at ~4 waves/SIMD (53% vs 85% occupancy, equal time),
// so the occupancy this gives up is free; the copies it avoids are not.
__global__ __launch_bounds__(256, 2)
void lattice_quant_kernel(const float* __restrict__ x,
                          const float* __restrict__ beta_p,
                          const float* __restrict__ eps,
                          float* __restrict__ out, int n) {
#pragma clang fp contract(off)
    int row = blockIdx.x * blockDim.x + threadIdx.x;
    if (row >= n) return;
    float beta = beta_p[0];

    const float4* px = (const float4*)(x + (size_t)row * 8);
    float4 a0 = px[0], a1 = px[1];
    const float4* pe = (const float4*)eps;
    float4 e0 = pe[0], e1 = pe[1];
    float2v eps2[4] = { {e0.x, e0.y}, {e0.z, e0.w}, {e1.x, e1.y}, {e1.z, e1.w} };

    float2v xl[4] = { {a0.x, a0.y}, {a0.z, a0.w}, {a1.x, a1.y}, {a1.z, a1.w} };
    if (beta != 1.0f) {                   // wave-uniform; beta==1 skips divs
#pragma unroll
        for (int p = 0; p < 4; ++p) { xl[p].x = xl[p].x / beta; xl[p].y = xl[p].y / beta; }
    }

    float2v xhat[4];

    float wgt = 1.0f;
#pragma unroll
    for (int l = 0; l < 3; ++l) {
        // ---- encode: quantize to E8 ----
        float2v xin[4], lat[4];
#pragma unroll
        for (int p = 0; p < 4; ++p) xin[p] = xl[p] + eps2[p];
        closest_point_E8v(xin, lat);

        // u = lat @ G_inv via forward substitution (exact fp32 == ref matmul)
        float u0 = 0.5f * lat[0].x;
        float u1 = lat[0].y + u0;
        float u2 = lat[1].x + u1;
        float u3 = lat[1].y + u2;
        float u4 = lat[2].x + u3;
        float u5 = lat[2].y + u4;
        float u6 = lat[3].x + u5;
        float s6 = ((u0 + u1) + (u2 + u3)) + ((u4 + u5) + u6);
        float u7 = fmaf(2.0f, lat[3].y, -s6);   // 2*lat7 exact -> == mul+sub
        float2v uv[4] = { {u0, u1}, {u2, u3}, {u4, u5}, {u6, u7} };

        // b = custom_round(fmod(u, 4)); fmod exact on quarter grid; the fma
        // is exact-by-proof (trunc*4 exact), so fused == ref's separate ops.
        // NOTE: u contains half/quarter-integers (u0 = lat0/2), so the croundv
        // here is NOT removable (cround(3.5)==4 quirk included).
        float2v b[4];
#pragma unroll
        for (int p = 0; p < 4; ++p) {
            float2v q = uv[p] * splat(0.25f);            // exact (pow2)
            float2v t4 = { truncf(q.x), truncf(q.y) };
            float2v m = vfma(t4, splat(-4.0f), uv[p]);   // == fmod(u,4) exact
            b[p] = croundv(m);
        }

        // ---- decode this layer: Gb = b @ rows (sparse, exact ints) ----
        float b0 = b[0].x, b1 = b[0].y, b2 = b[1].x, b3 = b[1].y;
        float b4 = b[2].x, b5 = b[2].y, b6 = b[3].x, b7 = b[3].y;
        float h = 0.5f * b7;
        float2v Gb[4];
        Gb[0].x = 2.0f * b0 - b1 + h;
        Gb[0].y = b1 - b2 + h;
        Gb[1].x = b2 - b3 + h;
        Gb[1].y = b3 - b4 + h;
        Gb[2].x = b4 - b5 + h;
        Gb[2].y = b5 - b6 + h;
        Gb[3].x = b6 + h;
        Gb[3].y = h;

        float2v gq[4], cp[4];
#pragma unroll
        for (int p = 0; p < 4; ++p) gq[p] = Gb[p] * splat(0.25f);
        closest_point_E8v(gq, cp);

#pragma unroll
        for (int p = 0; p < 4; ++p) {
            float2v xi = vfma(cp[p], splat(-4.0f), Gb[p]);  // Gb - 4*cp (exact)
            if (l == 0) {
                // layer 0: ref computes 0 + 1*xi = xi bitwise (xi never -0),
                // so a plain copy is bit-exact.
                xhat[p] = xi;
            } else {
                xhat[p] = vfma(xi, splat(wgt), xhat[p]);    // += wgt*xi (exact)
            }
        }

        // next layer input: lat / Q (exact)
#pragma unroll
        for (int p = 0; p < 4; ++p) xl[p] = lat[p] * splat(0.25f);
        wgt *= 4.0f;
    }

    // epilogue: beta==1 -> x*1 == x bitwise, skip the mul (wave-uniform)
    float2v o[4];
    if (beta != 1.0f) {
        float2v bv = splat(beta);
#pragma unroll
        for (int p = 0; p < 4; ++p) o[p] = xhat[p] * bv;
    } else {
#pragma unroll
        for (int p = 0; p < 4; ++p) o[p] = xhat[p];
    }
    float4 o0, o1;
    o0.x = o[0].x; o0.y = o[0].y; o0.z = o[1].x; o0.w = o[1].y;
    o1.x = o[2].x; o1.y = o[2].y; o1.z = o[3].x; o1.w = o[3].y;
    float4* po = (float4*)(out + (size_t)row * 8);
    po[0] = o0; po[1] = o1;
}

extern "C" void kernel_launch(void* const* d_in, const int* in_sizes, int n_in,
                              void* d_out, int out_size, void* d_ws, size_t ws_size,
                              hipStream_t stream) {
    const float* x      = (const float*)d_in[0];
    const float* beta_p = (const float*)d_in[1];
    // d_in[2] = G, d_in[3] = G_inv — structure hardcoded (fixed by reference)
    const float* eps    = (const float*)d_in[4];
    float* out = (float*)d_out;
    int n = in_sizes[0] / 8;
    int block = 256;
    int grid = (n + block - 1) / block;
    lattice_quant_kernel<<<grid, block, 0, stream>>>(x, beta_p, eps, out, n);
}

// Round 6
// 314.238 us; speedup vs baseline: 1.1344x; 1.0581x over previous
//
#include <hip/hip_runtime.h>
#include <math.h>

#define TINY_EPS 1.1920928955078125e-07f  // np.finfo(np.float32).eps = 2^-23

typedef float float2v __attribute__((ext_vector_type(2)));

// Native vector ops: on gfx950 LLVM selects v_pk_*_f32 from <2 x float> IR.
// All FP stays IEEE-exact: fp contract(off) everywhere; explicit single-rounded
// FMA only via __builtin_elementwise_fma where exactness is proven.
// Round-3 A/B proved this vector form beats pure-scalar by 14% (185 vs 212 us).
static __device__ __forceinline__ float2v vfma(float2v a, float2v b, float2v c) {
    return __builtin_elementwise_fma(a, b, c);
}
static __device__ __forceinline__ float2v splat(float s) { return (float2v){s, s}; }

// custom_round per component: floor((x - copysign(TINY,x)) + 0.5).
// (v - cs) is a single IEEE sub == ref's x - sign(x)*TINY.
static __device__ __forceinline__ float2v croundv(float2v v) {
#pragma clang fp contract(off)
    float2v cs = { copysignf(TINY_EPS, v.x), copysignf(TINY_EPS, v.y) };
    float2v t = (v - cs) + splat(0.5f);
    return (float2v){ floorf(t.x), floorf(t.y) };
}

// One D8 branch candidate: y = f + onehot(k)*sfm (+0.5 when SHIFTED).
// The onehot comes from a 256B LDS LUT (k in [0,8)) — offloads ~15 VALU
// slots/candidate (8 cmp + 8 cndmask) onto the idle LDS pipe.
// Bit-exactness: at i==k, fma(1, sfm, f) = fl(sfm + f) = exact integer add
// == ref's f + onehot*step; at i!=k, fma(0, sfm, f) adds +/-0 to f and f is
// never -0 (cround returns +0: the only zero-producing path is fl(-0.5+0.5)
// = +0). SHIFTED: ref computes (f + onehot*step) + 0.5 in that order; we do
// fma(...) + 0.5 — both adds exact (integers + 0.5), bitwise equal.
template <bool SHIFTED>
static __device__ __forceinline__ void d8_candidate(const float2v in[4], float2v y[4],
                                                    const float* __restrict__ lutp) {
#pragma clang fp contract(off)
    float2v f[4], w[4];
#pragma unroll
    for (int p = 0; p < 4; ++p) {
        f[p] = croundv(in[p]);
        w[p] = in[p] - f[p];              // exact (Sterbenz-type)
    }

    // parity of the integer sum — exact small ints, order-free
    float2v sp = (f[0] + f[1]) + (f[2] + f[3]);
    float s = sp.x + sp.y;
    int odd = ((int)s) & 1;

    // argmax |w|, FIRST index on ties — tournament tree (dep depth 3).
    // Left wins ties (>=) => lowest-indexed maximum, == jnp.argmax semantics.
    float v01, v23, v45, v67; int k01, k23, k45, k67;
    { bool ge = fabsf(w[0].x) >= fabsf(w[0].y); v01 = ge ? w[0].x : w[0].y; k01 = ge ? 0 : 1; }
    { bool ge = fabsf(w[1].x) >= fabsf(w[1].y); v23 = ge ? w[1].x : w[1].y; k23 = ge ? 2 : 3; }
    { bool ge = fabsf(w[2].x) >= fabsf(w[2].y); v45 = ge ? w[2].x : w[2].y; k45 = ge ? 4 : 5; }
    { bool ge = fabsf(w[3].x) >= fabsf(w[3].y); v67 = ge ? w[3].x : w[3].y; k67 = ge ? 6 : 7; }
    float va, vb; int ka, kb;
    { bool ge = fabsf(v01) >= fabsf(v23); va = ge ? v01 : v23; ka = ge ? k01 : k23; }
    { bool ge = fabsf(v45) >= fabsf(v67); vb = ge ? v45 : v67; kb = ge ? k45 : k67; }
    int k; float wk;
    { bool ge = fabsf(va) >= fabsf(vb); wk = ge ? va : vb; k = ge ? ka : kb; }

    // step = sign(wk) for wk!=0; for wk==0 all |w|==0 so k==0 and the tie
    // x-value is in[0].x (never -0.0 on any reachable path).
    float tsel = (wk != 0.0f) ? wk : -in[0].x;
    float sf = __int_as_float(0x3f800000 | (__float_as_int(tsel) & 0x80000000u));
    float sfm = odd ? sf : 0.0f;          // flip only when parity is odd

    // one-hot(k) from LDS (2x ds_read_b128; k and k+4 rows alias banks ->
    // 2-way conflict, which is free on CDNA4)
    const float4* lq = (const float4*)(lutp + (k << 3));
    float4 A = lq[0], B = lq[1];
    float2v sv = splat(sfm);
    y[0] = vfma((float2v){A.x, A.y}, sv, f[0]);
    y[1] = vfma((float2v){A.z, A.w}, sv, f[1]);
    y[2] = vfma((float2v){B.x, B.y}, sv, f[2]);
    y[3] = vfma((float2v){B.z, B.w}, sv, f[3]);
    if (SHIFTED) {
#pragma unroll
        for (int p = 0; p < 4; ++p) y[p] = y[p] + splat(0.5f);   // exact
    }
}

static __device__ __forceinline__ void closest_point_E8v(const float2v x[4], float2v y[4],
                                                         const float* __restrict__ lutp) {
#pragma clang fp contract(off)
    float2v y0[4], y1[4], xs[4];
    d8_candidate<false>(x, y0, lutp);
#pragma unroll
    for (int p = 0; p < 4; ++p) xs[p] = x[p] - splat(0.5f);
    d8_candidate<true>(xs, y1, lutp);      // (cand)+0.5 folded in

    // Distances from the ORIGINAL x; packed subs/squares, scalar tree adds in
    // numpy's exact pairwise order — vector-element pairs ARE the base pairs.
    float2v q0[4], q1[4];
#pragma unroll
    for (int p = 0; p < 4; ++p) {
        float2v e0 = x[p] - y0[p];
        q0[p] = e0 * e0;
        float2v e1 = x[p] - y1[p];
        q1[p] = e1 * e1;
    }
    float D0 = ((q0[0].x + q0[0].y) + (q0[1].x + q0[1].y)) +
               ((q0[2].x + q0[2].y) + (q0[3].x + q0[3].y));
    float D1 = ((q1[0].x + q1[0].y) + (q1[1].x + q1[1].y)) +
               ((q1[2].x + q1[2].y) + (q1[3].x + q1[3].y));
    bool pick0 = (D0 < D1);               // tie -> y1, as in ref
#pragma unroll
    for (int p = 0; p < 4; ++p) {
        float2v r;
        r.x = pick0 ? y0[p].x : y1[p].x;
        r.y = pick0 ? y0[p].y : y1[p].y;
        y[p] = r;
    }
}

__global__ __launch_bounds__(256)
void lattice_quant_kernel(const float* __restrict__ x,
                          const float* __restrict__ beta_p,
                          const float* __restrict__ eps,
                          float* __restrict__ out, int n) {
#pragma clang fp contract(off)
    // 256B one-hot LUT in LDS: lut[k][i] = (i==k) ? 1 : 0.
    // Init before any early return so __syncthreads is block-complete.
    __shared__ __align__(16) float lut[8][8];
    {
        int t = threadIdx.x;
        if (t < 64) lut[t >> 3][t & 7] = ((t >> 3) == (t & 7)) ? 1.0f : 0.0f;
    }
    __syncthreads();
    const float* lutp = &lut[0][0];

    int row = blockIdx.x * blockDim.x + threadIdx.x;
    if (row >= n) return;
    float beta = beta_p[0];

    const float4* px = (const float4*)(x + (size_t)row * 8);
    float4 a0 = px[0], a1 = px[1];
    const float4* pe = (const float4*)eps;
    float4 e0 = pe[0], e1 = pe[1];
    float2v eps2[4] = { {e0.x, e0.y}, {e0.z, e0.w}, {e1.x, e1.y}, {e1.z, e1.w} };

    float2v xl[4] = { {a0.x, a0.y}, {a0.z, a0.w}, {a1.x, a1.y}, {a1.z, a1.w} };
    if (beta != 1.0f) {                   // wave-uniform; beta==1 skips divs
#pragma unroll
        for (int p = 0; p < 4; ++p) { xl[p].x = xl[p].x / beta; xl[p].y = xl[p].y / beta; }
    }

    float2v xhat[4];

    float wgt = 1.0f;
#pragma unroll
    for (int l = 0; l < 3; ++l) {
        // ---- encode: quantize to E8 ----
        float2v xin[4], lat[4];
#pragma unroll
        for (int p = 0; p < 4; ++p) xin[p] = xl[p] + eps2[p];
        closest_point_E8v(xin, lat, lutp);

        // u = lat @ G_inv via forward substitution (exact fp32 == ref matmul)
        float u0 = 0.5f * lat[0].x;
        float u1 = lat[0].y + u0;
        float u2 = lat[1].x + u1;
        float u3 = lat[1].y + u2;
        float u4 = lat[2].x + u3;
        float u5 = lat[2].y + u4;
        float u6 = lat[3].x + u5;
        float s6 = ((u0 + u1) + (u2 + u3)) + ((u4 + u5) + u6);
        float u7 = fmaf(2.0f, lat[3].y, -s6);   // 2*lat7 exact -> == mul+sub
        float2v uv[4] = { {u0, u1}, {u2, u3}, {u4, u5}, {u6, u7} };

        // b = custom_round(fmod(u, 4)); fmod exact on half-integer grid; the
        // fma is exact-by-proof (trunc*4 exact), so fused == ref's separate ops.
        // NOTE: u contains half-integers (u0 = lat0/2), so the croundv here is
        // NOT removable (cround(3.5)==4 magnitude-dependent quirk included).
        float2v b[4];
#pragma unroll
        for (int p = 0; p < 4; ++p) {
            float2v q = uv[p] * splat(0.25f);            // exact (pow2)
            float2v t4 = { truncf(q.x), truncf(q.y) };
            float2v m = vfma(t4, splat(-4.0f), uv[p]);   // == fmod(u,4) exact
            b[p] = croundv(m);
        }

        // ---- decode this layer: Gb = b @ rows (sparse, exact ints) ----
        float b0 = b[0].x, b1 = b[0].y, b2 = b[1].x, b3 = b[1].y;
        float b4 = b[2].x, b5 = b[2].y, b6 = b[3].x, b7 = b[3].y;
        float h = 0.5f * b7;
        float2v Gb[4];
        Gb[0].x = 2.0f * b0 - b1 + h;
        Gb[0].y = b1 - b2 + h;
        Gb[1].x = b2 - b3 + h;
        Gb[1].y = b3 - b4 + h;
        Gb[2].x = b4 - b5 + h;
        Gb[2].y = b5 - b6 + h;
        Gb[3].x = b6 + h;
        Gb[3].y = h;

        float2v gq[4], cp[4];
#pragma unroll
        for (int p = 0; p < 4; ++p) gq[p] = Gb[p] * splat(0.25f);
        closest_point_E8v(gq, cp, lutp);

#pragma unroll
        for (int p = 0; p < 4; ++p) {
            float2v xi = vfma(cp[p], splat(-4.0f), Gb[p]);  // Gb - 4*cp (exact)
            if (l == 0) {
                // layer 0: ref computes 0 + 1*xi = xi bitwise (xi never -0),
                // so a plain copy is bit-exact.
                xhat[p] = xi;
            } else {
                xhat[p] = vfma(xi, splat(wgt), xhat[p]);    // += wgt*xi (exact)
            }
        }

        // next layer input: lat / Q (exact)
#pragma unroll
        for (int p = 0; p < 4; ++p) xl[p] = lat[p] * splat(0.25f);
        wgt *= 4.0f;
    }

    // epilogue: beta==1 -> x*1 == x bitwise, skip the mul (wave-uniform)
    float2v o[4];
    if (beta != 1.0f) {
        float2v bv = splat(beta);
#pragma unroll
        for (int p = 0; p < 4; ++p) o[p] = xhat[p] * bv;
    } else {
#pragma unroll
        for (int p = 0; p < 4; ++p) o[p] = xhat[p];
    }
    float4 o0, o1;
    o0.x = o[0].x; o0.y = o[0].y; o0.z = o[1].x; o0.w = o[1].y;
    o1.x = o[2].x; o1.y = o[2].y; o1.z = o[3].x; o1.w = o[3].y;
    float4* po = (float4*)(out + (size_t)row * 8);
    po[0] = o0; po[1] = o1;
}

extern "C" void kernel_launch(void* const* d_in, const int* in_sizes, int n_in,
                              void* d_out, int out_size, void* d_ws, size_t ws_size,
                              hipStream_t stream) {
    const float* x      = (const float*)d_in[0];
    const float* beta_p = (const float*)d_in[1];
    // d_in[2] = G, d_in[3] = G_inv — structure hardcoded (fixed by reference)
    const float* eps    = (const float*)d_in[4];
    float* out = (float*)d_out;
    int n = in_sizes[0] / 8;
    int block = 256;
    int grid = (n + block - 1) / block;
    lattice_quant_kernel<<<grid, block, 0, stream>>>(x, beta_p, eps, out, n);
}